// Round 6
// baseline (374.190 us; speedup 1.0000x reference)
//
#include <hip/hip_runtime.h>

// GCN 3-layer fused pipeline for MI355X.
// N=50000 nodes, E=800000 edges, F=128 features.
// edge_index staged as int32, layout [row[0..E), col[0..E)].
// Per layer: g = dinv * (X' @ W)  (X' = relu(dinv*agg_prev + b_prev) fused into load)
//            agg[v] = g[v] + sum_{in-edges} g[src]  (CSR gather, no atomics)
// R2: k_agg wave-per-node float4 gathers, 4-deep: 85->58us (3.7 TB/s, still latency-bound;
//     FETCH 185MB = 8-XCD refetch floor, so bytes are fixed -> raise concurrency).
// R5: k_agg grid-stride persistent waves + 8-deep masked pipeline (no serial remainder);
//     k_gemm LDS 48->32KB (5 blocks/CU) + b128 X broadcast reads.

__global__ __launch_bounds__(256) void k_prep(const int* __restrict__ ei,
                                              int* __restrict__ cnt, int E, int N) {
  int e = blockIdx.x * 256 + threadIdx.x;
  if (e < E) {
    unsigned c = (unsigned)ei[E + e];
    if (c < (unsigned)N) atomicAdd(&cnt[c], 1);
  }
}

// block-local exclusive scan of cnt; also emits dinv (fused, saves a launch)
__global__ __launch_bounds__(256) void k_scan1(const int* __restrict__ cnt, int* __restrict__ offs,
                                               int* __restrict__ bsum, float* __restrict__ dinv, int N) {
  __shared__ int s[256];
  int tid = threadIdx.x;
  int i = blockIdx.x * 256 + tid;
  int v = (i < N) ? cnt[i] : 0;
  if (i < N) dinv[i] = rsqrtf((float)(v + 1));  // +1 self loop; always > 0
  s[tid] = v;
  __syncthreads();
  for (int d = 1; d < 256; d <<= 1) {
    int t = (tid >= d) ? s[tid - d] : 0;
    __syncthreads();
    s[tid] += t;
    __syncthreads();
  }
  if (i < N) offs[i] = s[tid] - v;
  if (tid == 255) bsum[blockIdx.x] = s[255];
}

__global__ __launch_bounds__(256) void k_scan2(int* __restrict__ bsum, int B) {
  __shared__ int s[256];
  int tid = threadIdx.x;
  int v = (tid < B) ? bsum[tid] : 0;
  s[tid] = v;
  __syncthreads();
  for (int d = 1; d < 256; d <<= 1) {
    int t = (tid >= d) ? s[tid - d] : 0;
    __syncthreads();
    s[tid] += t;
    __syncthreads();
  }
  if (tid < B) bsum[tid] = s[tid] - v;
}

__global__ __launch_bounds__(256) void k_scan3(int* __restrict__ offs, const int* __restrict__ bsum,
                                               int* __restrict__ cursor, int N, int E) {
  int i = blockIdx.x * 256 + threadIdx.x;
  if (i < N) {
    int o = offs[i] + bsum[blockIdx.x];
    offs[i] = o;
    cursor[i] = o;
  }
  if (i == 0) offs[N] = E;
}

__global__ __launch_bounds__(256) void k_fill(const int* __restrict__ ei,
                                              int* __restrict__ cursor, int* __restrict__ csr_src,
                                              int E, int N) {
  int e = blockIdx.x * 256 + threadIdx.x;
  if (e < E) {
    unsigned r = (unsigned)ei[e];
    unsigned c = (unsigned)ei[E + e];
    if (c < (unsigned)N && r < (unsigned)N) {
      int p = atomicAdd(&cursor[c], 1);
      csr_src[p] = (int)r;
    }
  }
}

// GEMM: G[row][col] = dinv[row] * sum_k X'[row][k] * W[k][col]
// MODE 0: X' = X.  MODE 1: X'[r][k] = relu(dinv[r]*X[r][k] + bias[k]).
// 256 thr -> 32 rows x 128 cols; thread = 4 rows x 4 cols.
// LDS 32KB (Wl 32x128 + Xl 32x128) -> 5 blocks/CU. X reads are b128 broadcasts.
template <int MODE>
__global__ __launch_bounds__(256) void k_gemm(const float* __restrict__ X, const float* __restrict__ W,
                                              const float* __restrict__ dinv, const float* __restrict__ bias,
                                              float* __restrict__ G, int N) {
  __shared__ float Wl[32 * 128];   // 16 KB (K-chunk of 32)
  __shared__ float Xl[32 * 128];   // 16 KB
  int tid = threadIdx.x;
  int row0 = blockIdx.x * 32;

  for (int i = tid; i < 1024; i += 256) {
    int r = i >> 5;
    int cc = i & 31;
    int grow = row0 + r;
    int gr = (grow < N) ? grow : (N - 1);
    float4 v = ((const float4*)X)[(size_t)gr * 32 + cc];
    if (MODE == 1) {
      float di = dinv[gr];
      v.x = fmaxf(fmaf(di, v.x, bias[cc * 4 + 0]), 0.f);
      v.y = fmaxf(fmaf(di, v.y, bias[cc * 4 + 1]), 0.f);
      v.z = fmaxf(fmaf(di, v.z, bias[cc * 4 + 2]), 0.f);
      v.w = fmaxf(fmaf(di, v.w, bias[cc * 4 + 3]), 0.f);
    }
    ((float4*)Xl)[i] = v;
  }

  int cg = tid & 31;
  int rg = tid >> 5;
  float acc[4][4];
#pragma unroll
  for (int a = 0; a < 4; a++)
#pragma unroll
    for (int b = 0; b < 4; b++) acc[a][b] = 0.f;

  for (int kt = 0; kt < 4; kt++) {
    __syncthreads();  // Xl ready (kt=0) / previous Wl reads done
    for (int i = tid; i < 1024; i += 256)
      ((float4*)Wl)[i] = ((const float4*)W)[kt * 1024 + i];
    __syncthreads();
#pragma unroll
    for (int k4 = 0; k4 < 8; k4++) {
      float4 wv[4];
      float4 xv[4];
#pragma unroll
      for (int kk = 0; kk < 4; kk++)
        wv[kk] = ((const float4*)(Wl + (k4 * 4 + kk) * 128))[cg];
#pragma unroll
      for (int r = 0; r < 4; r++)
        xv[r] = *(const float4*)(Xl + (rg * 4 + r) * 128 + kt * 32 + k4 * 4);
#pragma unroll
      for (int r = 0; r < 4; r++) {
        float xr0 = xv[r].x, xr1 = xv[r].y, xr2 = xv[r].z, xr3 = xv[r].w;
        acc[r][0] = fmaf(xr0, wv[0].x, acc[r][0]);
        acc[r][1] = fmaf(xr0, wv[0].y, acc[r][1]);
        acc[r][2] = fmaf(xr0, wv[0].z, acc[r][2]);
        acc[r][3] = fmaf(xr0, wv[0].w, acc[r][3]);
        acc[r][0] = fmaf(xr1, wv[1].x, acc[r][0]);
        acc[r][1] = fmaf(xr1, wv[1].y, acc[r][1]);
        acc[r][2] = fmaf(xr1, wv[1].z, acc[r][2]);
        acc[r][3] = fmaf(xr1, wv[1].w, acc[r][3]);
        acc[r][0] = fmaf(xr2, wv[2].x, acc[r][0]);
        acc[r][1] = fmaf(xr2, wv[2].y, acc[r][1]);
        acc[r][2] = fmaf(xr2, wv[2].z, acc[r][2]);
        acc[r][3] = fmaf(xr2, wv[2].w, acc[r][3]);
        acc[r][0] = fmaf(xr3, wv[3].x, acc[r][0]);
        acc[r][1] = fmaf(xr3, wv[3].y, acc[r][1]);
        acc[r][2] = fmaf(xr3, wv[3].z, acc[r][2]);
        acc[r][3] = fmaf(xr3, wv[3].w, acc[r][3]);
      }
    }
  }

  for (int ri = 0; ri < 4; ri++) {
    int grow = row0 + rg * 4 + ri;
    if (grow < N) {
      float di = dinv[grow];
      float4 o;
      o.x = di * acc[ri][0];
      o.y = di * acc[ri][1];
      o.z = di * acc[ri][2];
      o.w = di * acc[ri][3];
      ((float4*)(G + (size_t)grow * 128))[cg] = o;
    }
  }
}

// agg[v][f] = g[v][f] + sum over in-edges g[src][f].
// Grid-stride wave-per-node. Half-waves own alternate edges; 8-deep masked
// pipeline (clamped index + fmaf scale) -> no serial remainder, 16 rows
// in flight per wave. Fetch volume is at the 8-XCD refetch floor (~185MB);
// this attacks service rate via MLP.
__global__ __launch_bounds__(256) void k_agg(const float* __restrict__ g, const int* __restrict__ offs,
                                             const int* __restrict__ csr_src, float* __restrict__ agg,
                                             int N, int nw) {
  int gw = (blockIdx.x * 256 + threadIdx.x) >> 6;  // global wave id
  int lane = threadIdx.x & 63;
  int half = lane >> 5;      // 0 or 1
  int fc = lane & 31;        // float4 index within row
  const float4* __restrict__ G4 = (const float4*)g;

  for (int v = gw; v < N; v += nw) {
    int s0 = offs[v], s1 = offs[v + 1];
    float4 a0 = make_float4(0.f, 0.f, 0.f, 0.f);
    float4 a1 = make_float4(0.f, 0.f, 0.f, 0.f);
    if (half == 0) a0 = G4[(size_t)v * 32 + fc];  // self row
    int last = s1 - 1;

    for (int i = s0 + half; i < s1; i += 16) {
      int idx[8];
      float sc[8];
#pragma unroll
      for (int k = 0; k < 8; k++) {
        int j = i + 2 * k;
        int jc = (j < last) ? j : last;   // clamp: wasted slots re-read same row (L1 hit)
        idx[k] = csr_src[jc];
        sc[k] = (j < s1) ? 1.f : 0.f;
      }
      float4 r[8];
#pragma unroll
      for (int k = 0; k < 8; k++) r[k] = G4[(size_t)idx[k] * 32 + fc];
#pragma unroll
      for (int k = 0; k < 8; k += 2) {
        a0.x = fmaf(sc[k], r[k].x, a0.x);
        a0.y = fmaf(sc[k], r[k].y, a0.y);
        a0.z = fmaf(sc[k], r[k].z, a0.z);
        a0.w = fmaf(sc[k], r[k].w, a0.w);
        a1.x = fmaf(sc[k + 1], r[k + 1].x, a1.x);
        a1.y = fmaf(sc[k + 1], r[k + 1].y, a1.y);
        a1.z = fmaf(sc[k + 1], r[k + 1].z, a1.z);
        a1.w = fmaf(sc[k + 1], r[k + 1].w, a1.w);
      }
    }
    a0.x += a1.x; a0.y += a1.y; a0.z += a1.z; a0.w += a1.w;

    // combine the two halves (lane ^ 32)
    a0.x += __shfl_xor(a0.x, 32, 64);
    a0.y += __shfl_xor(a0.y, 32, 64);
    a0.z += __shfl_xor(a0.z, 32, 64);
    a0.w += __shfl_xor(a0.w, 32, 64);

    if (half == 0) ((float4*)agg)[(size_t)v * 32 + fc] = a0;
  }
}

// layer 3 GEMV: g3[r] = dinv[r] * sum_k relu(dinv[r]*agg2[r][k] + b2[k]) * W3[k]
__global__ __launch_bounds__(256) void k_gemv3(const float* __restrict__ agg2, const float* __restrict__ W3,
                                               const float* __restrict__ dinv, const float* __restrict__ b2,
                                               float* __restrict__ g3, int N) {
  int wave = threadIdx.x >> 6;
  int lane = threadIdx.x & 63;
  int r = blockIdx.x * 4 + wave;
  if (r >= N) return;
  float di = dinv[r];
  float2 xv = ((const float2*)agg2)[(size_t)r * 64 + lane];
  float2 wv = ((const float2*)W3)[lane];
  float2 bb = ((const float2*)b2)[lane];
  float v0 = fmaxf(fmaf(di, xv.x, bb.x), 0.f);
  float v1 = fmaxf(fmaf(di, xv.y, bb.y), 0.f);
  float s = v0 * wv.x + v1 * wv.y;
  for (int d = 32; d > 0; d >>= 1) s += __shfl_down(s, d, 64);
  if (lane == 0) g3[r] = di * s;
}

__global__ __launch_bounds__(256) void k_agg3(const float* __restrict__ g3, const int* __restrict__ offs,
                                              const int* __restrict__ csr_src, const float* __restrict__ dinv,
                                              const float* __restrict__ b3, float* __restrict__ out, int N) {
  int v = blockIdx.x * 256 + threadIdx.x;
  if (v < N) {
    float acc = g3[v];
    int i = offs[v], s1 = offs[v + 1];
    for (; i + 3 < s1; i += 4) {
      int e0 = csr_src[i], e1 = csr_src[i + 1], e2 = csr_src[i + 2], e3 = csr_src[i + 3];
      float r0 = g3[e0], r1 = g3[e1], r2 = g3[e2], r3 = g3[e3];
      acc += r0 + r1 + r2 + r3;
    }
    for (; i < s1; i++) acc += g3[csr_src[i]];
    out[v] = dinv[v] * acc + b3[0];
  }
}

extern "C" void kernel_launch(void* const* d_in, const int* in_sizes, int n_in,
                              void* d_out, int out_size, void* d_ws, size_t ws_size,
                              hipStream_t stream) {
  const float* x = (const float*)d_in[0];
  const int* ei = (const int*)d_in[1];
  const float* W1 = (const float*)d_in[2];
  const float* b1 = (const float*)d_in[3];
  const float* W2 = (const float*)d_in[4];
  const float* b2 = (const float*)d_in[5];
  const float* W3 = (const float*)d_in[6];
  const float* b3 = (const float*)d_in[7];
  float* out = (float*)d_out;

  int N = in_sizes[0] / 128;  // 50000
  int E = in_sizes[1] / 2;    // 800000

  char* base = (char*)d_ws;
  size_t off = 0;
  auto alloc = [&](size_t bytes) -> void* {
    void* p = base + off;
    off += (bytes + 255) & ~(size_t)255;
    return p;
  };
  int* cnt = (int*)alloc((size_t)N * 4);
  int* offs = (int*)alloc(((size_t)N + 1) * 4);
  int* cursor = (int*)alloc((size_t)N * 4);
  int* csr = (int*)alloc((size_t)E * 4);
  float* dinv = (float*)alloc((size_t)N * 4);
  int* bsum = (int*)alloc(4096 * 4);
  float* bufA = (float*)alloc((size_t)N * 128 * 4);
  float* bufB = (float*)alloc((size_t)N * 128 * 4);
  float* g3 = (float*)alloc((size_t)N * 4);
  (void)ws_size;

  hipMemsetAsync(cnt, 0, (size_t)N * 4, stream);

  int gE = (E + 255) / 256;
  int gN = (N + 255) / 256;
  k_prep<<<gE, 256, 0, stream>>>(ei, cnt, E, N);
  k_scan1<<<gN, 256, 0, stream>>>(cnt, offs, bsum, dinv, N);
  k_scan2<<<1, 256, 0, stream>>>(bsum, gN);
  k_scan3<<<gN, 256, 0, stream>>>(offs, bsum, cursor, N, E);
  k_fill<<<gE, 256, 0, stream>>>(ei, cursor, csr, E, N);

  int gG = (N + 31) / 32;
  int gA = 2048;              // persistent-ish: 8192 waves, ~6 nodes each
  int nwaves = gA * 4;
  k_gemm<0><<<gG, 256, 0, stream>>>(x, W1, dinv, nullptr, bufA, N);
  k_agg<<<gA, 256, 0, stream>>>(bufA, offs, csr, bufB, N, nwaves);
  k_gemm<1><<<gG, 256, 0, stream>>>(bufB, W2, dinv, b1, bufA, N);
  k_agg<<<gA, 256, 0, stream>>>(bufA, offs, csr, bufB, N, nwaves);
  int gV = (N + 3) / 4;
  k_gemv3<<<gV, 256, 0, stream>>>(bufB, W3, dinv, b2, g3, N);
  k_agg3<<<gN, 256, 0, stream>>>(g3, offs, csr, dinv, b3, out, N);
}